// Round 7
// baseline (662.792 us; speedup 1.0000x reference)
//
#include <hip/hip_runtime.h>

typedef __attribute__((ext_vector_type(8))) short bf16x8;
typedef __attribute__((ext_vector_type(4))) float f32x4;
typedef unsigned int u32;
typedef unsigned short u16;

__device__ __forceinline__ u16 f2bf(float f) {
  u32 u = __float_as_uint(f);
  u += 0x7fffu + ((u >> 16) & 1u);   // RNE
  return (u16)(u >> 16);
}
__device__ __forceinline__ u32 pack2(float a, float b) {
  return (u32)f2bf(a) | ((u32)f2bf(b) << 16);
}
__device__ __forceinline__ void gload_lds16(const void* g, void* l) {
  __builtin_amdgcn_global_load_lds(
      (const __attribute__((address_space(1))) u32*)g,
      (__attribute__((address_space(3))) u32*)l, 16, 0, 0);
}

// ---------------- pre-pass: f32 -> bf16 (K, W) ----------------
__global__ void cvt_bf16_kernel(const float* __restrict__ in, u16* __restrict__ out,
                                long long n8) {
  long long i = (long long)blockIdx.x * blockDim.x + threadIdx.x;
  if (i >= n8) return;
  const float4* p = (const float4*)in + i * 2;
  float4 a = p[0], b = p[1];
  uint4 o;
  o.x = pack2(a.x, a.y); o.y = pack2(a.z, a.w);
  o.z = pack2(b.x, b.y); o.w = pack2(b.z, b.w);
  ((uint4*)out)[i] = o;
}

// ---------------- pre-pass: V[b][n][d] -> Vt[b][d][n] (bf16) ----------------
__global__ __launch_bounds__(256)
void transpose_v_kernel(const float* __restrict__ V, u16* __restrict__ Vt) {
  __shared__ float tile[64][65];
  const int n0 = blockIdx.x * 64, d0 = blockIdx.y * 64, bat = blockIdx.z;
  const int t = threadIdx.x;
  const int rr = t >> 4, cc = (t & 15) * 4;
#pragma unroll
  for (int i = 0; i < 4; ++i) {
    int r = i * 16 + rr;
    float4 v = *(const float4*)(V + ((size_t)(bat * 2048 + n0 + r)) * 512 + d0 + cc);
    tile[r][cc + 0] = v.x; tile[r][cc + 1] = v.y;
    tile[r][cc + 2] = v.z; tile[r][cc + 3] = v.w;
  }
  __syncthreads();
#pragma unroll
  for (int i = 0; i < 4; ++i) {
    int dr = i * 16 + rr;
    uint2 o;
    o.x = pack2(tile[cc + 0][dr], tile[cc + 1][dr]);
    o.y = pack2(tile[cc + 2][dr], tile[cc + 3][dr]);
    *(uint2*)(Vt + ((size_t)(bat * 512 + d0 + dr)) * 2048 + n0 + cc) = o;
  }
}

// ------- fused flash attention + projection (REAL 16 waves/CU):
//   R = relu(softmax(QK^T*s) @ V);  Out = a*R + b*relu((V-R) @ W^T)
// Grid 512 blocks (8 bat x 64 q-tiles of 32 rows) x 512 thr -> 4096 waves
// = 16 waves/CU (4/SIMD), 2 independent barrier domains per CU.
// Single K buffer (no dbuf): K(it+1) DMA issued after bar1 (K(it) dead),
// drained by bar2's implicit vmcnt(0). Q loads global->reg (no LDS scratch).
// LDS (bytes), total 79264 -> 2 blocks/CU (158.5KB of 160KB):
//  Ks [64][1024B] bf16 XOR-swz @0     (65536)  (T=V-R tile in epilogue)
//  Ss [32][68] f32             @65536 (8704)
//  Ps [32][144B] bf16          @74240 (4608)
//  mrow/lrow/resc f32[32]      @78848/78976/79104
//  flg u32[8]                  @79232
#define ATT_LDS 79264

__global__ __launch_bounds__(512, 4)
void attn_kernel(const float* __restrict__ Qf, const u16* __restrict__ Kb,
                 const u16* __restrict__ Vtg, const float* __restrict__ Vg,
                 const u16* __restrict__ Wb, const float* __restrict__ sp,
                 const float* __restrict__ ap, const float* __restrict__ bp,
                 float* __restrict__ Out) {
  extern __shared__ char smem[];
  u16* Ks = (u16*)smem;
  float* Ss = (float*)(smem + 65536);
  u16* Ps = (u16*)(smem + 74240);
  float* mrow = (float*)(smem + 78848);
  float* lrow = (float*)(smem + 78976);
  float* resc = (float*)(smem + 79104);
  u32* flg = (u32*)(smem + 79232);

  const int tid = threadIdx.x, lane = tid & 63, wid = tid >> 6;
  const int bat = blockIdx.x, q0 = blockIdx.y * 32;  // blockIdx.x==bat -> XCD-batch locality
  const float scale = sp[0] * 0.04419417382415922f;  // 1/sqrt(512)
  const int l15 = lane & 15, l4 = lane >> 4;
  const int srow = tid >> 4, sseg = tid & 15;        // softmax: 16 thr/row, 32 rows
  const int rwD = wid >> 2, cwD = wid & 3;           // QK^T wave tile: 16q x 16kv

  // ---- prologue: Q direct global->reg, pre-scaled f32 -> bf16 fragments ----
  bf16x8 qf[16];
  {
    const float* qsrc = Qf + ((size_t)(bat * 2048 + q0 + rwD * 16 + l15)) * 512;
#pragma unroll
    for (int ks = 0; ks < 16; ++ks) {
      float4 x0 = *(const float4*)(qsrc + ks * 32 + l4 * 8);
      float4 x1 = *(const float4*)(qsrc + ks * 32 + l4 * 8 + 4);
      uint4 w;
      w.x = pack2(x0.x * scale, x0.y * scale); w.y = pack2(x0.z * scale, x0.w * scale);
      w.z = pack2(x1.x * scale, x1.y * scale); w.w = pack2(x1.z * scale, x1.w * scale);
      qf[ks] = *(bf16x8*)&w;
    }
  }

  // ---- stage K(0) via global_load_lds (source pre-swizzled per lane) ----
#pragma unroll
  for (int j = 0; j < 8; ++j) {
    int row = wid * 8 + j;
    gload_lds16(Kb + ((size_t)(bat * 2048 + row)) * 512 + ((lane ^ (row & 7)) * 8),
                (char*)Ks + row * 1024);
  }
  if (tid < 32) { mrow[tid] = -1e30f; lrow[tid] = 0.f; }

  f32x4 o[2][4];
#pragma unroll
  for (int a = 0; a < 2; ++a)
#pragma unroll
    for (int b = 0; b < 4; ++b) o[a][b] = (f32x4){0.f, 0.f, 0.f, 0.f};

  __syncthreads();  // K(0) resident + visible

  const int swB = (l15 & 7) << 4;

  for (int it = 0; it < 32; ++it) {
    // ---- QK^T: wave = 16 q-rows x 16 kv-cols, K=512, even/odd acc chains ----
    {
      f32x4 se = (f32x4){0.f, 0.f, 0.f, 0.f};
      f32x4 so = (f32x4){0.f, 0.f, 0.f, 0.f};
      const char* kb = (const char*)Ks + (cwD * 16 + l15) * 1024;
      __builtin_amdgcn_s_setprio(1);
#pragma unroll
      for (int ks = 0; ks < 16; ks += 2) {
        const int offe = (ks * 64 + l4 * 16) ^ swB;
        const int offo = ((ks + 1) * 64 + l4 * 16) ^ swB;
        bf16x8 be = *(const bf16x8*)(kb + offe);
        bf16x8 bo = *(const bf16x8*)(kb + offo);
        se = __builtin_amdgcn_mfma_f32_16x16x32_bf16(qf[ks], be, se, 0, 0, 0);
        so = __builtin_amdgcn_mfma_f32_16x16x32_bf16(qf[ks + 1], bo, so, 0, 0, 0);
      }
      __builtin_amdgcn_s_setprio(0);
      f32x4 s = se + so;
      const int r0 = rwD * 16 + l4 * 4;
      const int c0 = cwD * 16 + l15;
#pragma unroll
      for (int j = 0; j < 4; ++j) Ss[(r0 + j) * 68 + c0] = s[j];
    }
    __syncthreads();  // bar1: Ss visible; all K(it) reads complete

    // ---- stage K(it+1) into the SAME buffer (K(it) dead past bar1) ----
    if (it < 31) {
      const int kv1 = (it + 1) * 64;
#pragma unroll
      for (int j = 0; j < 8; ++j) {
        int row = wid * 8 + j;
        gload_lds16(Kb + ((size_t)(bat * 2048 + kv1 + row)) * 512 + ((lane ^ (row & 7)) * 8),
                    (char*)Ks + row * 1024);
      }
    }

    // ---- online softmax with defer-max (THR=8): 16 threads/row, 4 cols each ----
    {
      const int row = srow, g = sseg;
      float4 sv = *(const float4*)(Ss + row * 68 + g * 4);
      float mt = fmaxf(fmaxf(sv.x, sv.y), fmaxf(sv.z, sv.w));
#pragma unroll
      for (int off = 1; off < 16; off <<= 1) mt = fmaxf(mt, __shfl_xor(mt, off));
      const float mold = mrow[row];
      const bool exceed = (mt > mold + 8.0f);
      const float mnew = exceed ? mt : mold;  // deferred max; P bounded by e^8
      float p0 = __expf(sv.x - mnew), p1 = __expf(sv.y - mnew);
      float p2 = __expf(sv.z - mnew), p3 = __expf(sv.w - mnew);
      float ps = (p0 + p1) + (p2 + p3);
#pragma unroll
      for (int off = 1; off < 16; off <<= 1) ps += __shfl_xor(ps, off);
      if (g == 0) {
        float rs = exceed ? __expf(mold - mnew) : 1.0f;
        resc[row] = rs;
        lrow[row] = lrow[row] * rs + ps;
        mrow[row] = mnew;
      }
      int ex = __any(g == 0 && exceed);  // wave-uniform
      if (lane == 0) flg[wid] = ex ? 1u : 0u;
      uint2 pw;
      pw.x = pack2(p0, p1); pw.y = pack2(p2, p3);
      *(uint2*)((char*)Ps + row * 144 + g * 8) = pw;
    }
    __syncthreads();  // bar2: Ps/flags visible; K(it+1) DMA drained

    // ---- PV: conditional rescale, then wave = 32 q-rows x 64 d-cols, k=64 ----
    {
      uint4 vr[8];
#pragma unroll
      for (int s = 0; s < 2; ++s)
#pragma unroll
        for (int cf = 0; cf < 4; ++cf)
          vr[s * 4 + cf] = *(const uint4*)(Vtg +
              ((size_t)(bat * 512 + wid * 64 + cf * 16 + l15)) * 2048 +
              it * 64 + s * 32 + l4 * 8);
      const uint4* fp = (const uint4*)flg;
      uint4 fa = fp[0], fb = fp[1];
      u32 anyr = fa.x | fa.y | fa.z | fa.w | fb.x | fb.y | fb.z | fb.w;
      if (anyr) {
#pragma unroll
        for (int fr = 0; fr < 2; ++fr) {
          f32x4 rf = *(const f32x4*)(resc + fr * 16 + l4 * 4);
#pragma unroll
          for (int cf = 0; cf < 4; ++cf)
#pragma unroll
            for (int j = 0; j < 4; ++j) o[fr][cf][j] *= rf[j];
        }
      }
#pragma unroll
      for (int s = 0; s < 2; ++s) {
        bf16x8 pa[2];
#pragma unroll
        for (int fr = 0; fr < 2; ++fr)
          pa[fr] = *(const bf16x8*)((const char*)Ps + (fr * 16 + l15) * 144 + s * 64 + l4 * 16);
        __builtin_amdgcn_s_setprio(1);
#pragma unroll
        for (int fr = 0; fr < 2; ++fr)
#pragma unroll
          for (int cf = 0; cf < 4; ++cf)
            o[fr][cf] = __builtin_amdgcn_mfma_f32_16x16x32_bf16(
                pa[fr], *(const bf16x8*)&vr[s * 4 + cf], o[fr][cf], 0, 0, 0);
        __builtin_amdgcn_s_setprio(0);
      }
    }
    // no trailing barrier: QK^T(it+1) reads Ks written pre-bar2; Ss(it+1) writes
    // ordered after all softmax(it) Ss reads by bar2.
  }

  // ======== fused epilogue ========
  // R = relu(O/l) in regs; T = V-R -> Ks span (bf16, swizzled);
  // C = T @ W^T; Out = a*R + b*relu(C)
  const float av = ap[0], bv = bp[0];
#pragma unroll
  for (int fr = 0; fr < 2; ++fr) {
    f32x4 lv = *(const f32x4*)(lrow + fr * 16 + l4 * 4);
    f32x4 inv;
#pragma unroll
    for (int j = 0; j < 4; ++j) inv[j] = 1.f / lv[j];
#pragma unroll
    for (int cf = 0; cf < 4; ++cf)
#pragma unroll
      for (int j = 0; j < 4; ++j)
        o[fr][cf][j] = fmaxf(o[fr][cf][j] * inv[j], 0.f);  // o now holds R
  }
  // write T = V - R (swizzled bf16) into Ks region (dead: PV reads only Ps/V)
  {
    u16* Ts = (u16*)smem;
#pragma unroll
    for (int fr = 0; fr < 2; ++fr)
#pragma unroll
      for (int cf = 0; cf < 4; ++cf) {
        const int col = wid * 64 + cf * 16 + l15;
#pragma unroll
        for (int j = 0; j < 4; ++j) {
          const int row = fr * 16 + l4 * 4 + j;
          float v = Vg[((size_t)(bat * 2048 + q0 + row)) * 512 + col];
          u16 t = f2bf(v - o[fr][cf][j]);
          *(u16*)((char*)Ts + row * 1024 + ((col * 2) ^ ((row & 7) << 4))) = t;
        }
      }
  }
  __syncthreads();  // T tile complete

  // projection GEMM: wave owns 32q x 64o (o-cols wid*64..+64), k=512
  f32x4 c2[2][4];
#pragma unroll
  for (int a = 0; a < 2; ++a)
#pragma unroll
    for (int b = 0; b < 4; ++b) c2[a][b] = (f32x4){0.f, 0.f, 0.f, 0.f};
  {
    const u16* Ts = (u16*)smem;
#pragma unroll
    for (int ks = 0; ks < 16; ++ks) {
      bf16x8 aT[2];
#pragma unroll
      for (int fr = 0; fr < 2; ++fr) {
        const int row = fr * 16 + l15;
        aT[fr] = *(const bf16x8*)((const char*)Ts + row * 1024 +
                                  ((ks * 64 + l4 * 16) ^ ((row & 7) << 4)));
      }
#pragma unroll
      for (int cf = 0; cf < 4; ++cf) {
        const int orow = wid * 64 + cf * 16 + l15;
        bf16x8 bw = *(const bf16x8*)(Wb + (size_t)orow * 512 + ks * 32 + l4 * 8);
#pragma unroll
        for (int fr = 0; fr < 2; ++fr)
          c2[fr][cf] = __builtin_amdgcn_mfma_f32_16x16x32_bf16(aT[fr], bw, c2[fr][cf], 0, 0, 0);
      }
    }
  }
  // combine + store
#pragma unroll
  for (int fr = 0; fr < 2; ++fr)
#pragma unroll
    for (int cf = 0; cf < 4; ++cf) {
      const int col = wid * 64 + cf * 16 + l15;
#pragma unroll
      for (int j = 0; j < 4; ++j) {
        const int row = fr * 16 + l4 * 4 + j;
        float c = fmaxf(c2[fr][cf][j], 0.f);
        Out[((size_t)(bat * 2048 + q0 + row)) * 512 + col] = av * o[fr][cf][j] + bv * c;
      }
    }
}

extern "C" void kernel_launch(void* const* d_in, const int* in_sizes, int n_in,
                              void* d_out, int out_size, void* d_ws, size_t ws_size,
                              hipStream_t stream) {
  const float* Q = (const float*)d_in[0];
  const float* K = (const float*)d_in[1];
  const float* V = (const float*)d_in[2];
  const float* W = (const float*)d_in[3];
  const float* sp = (const float*)d_in[4];
  const float* ap = (const float*)d_in[5];
  const float* bp = (const float*)d_in[6];
  float* out = (float*)d_out;

  const long long tEl = 8LL * 2048 * 512;  // 8388608 elems per tensor
  u16* Kb = (u16*)d_ws;
  u16* Vt = Kb + tEl;
  u16* Wb = Vt + tEl;

  cvt_bf16_kernel<<<4096, 256, 0, stream>>>(K, Kb, tEl / 8);
  cvt_bf16_kernel<<<128, 256, 0, stream>>>(W, Wb, (512LL * 512) / 8);
  transpose_v_kernel<<<dim3(32, 8, 8), 256, 0, stream>>>(V, Vt);

  hipFuncSetAttribute(reinterpret_cast<const void*>(attn_kernel),
                      hipFuncAttributeMaxDynamicSharedMemorySize, ATT_LDS);
  attn_kernel<<<dim3(8, 64), 512, ATT_LDS, stream>>>(Q, Kb, Vt, V, Wb, sp, ap, bp, out);
}

// Round 8
// 324.022 us; speedup vs baseline: 2.0455x; 2.0455x over previous
//
#include <hip/hip_runtime.h>

typedef __attribute__((ext_vector_type(8))) short bf16x8;
typedef __attribute__((ext_vector_type(4))) float f32x4;
typedef unsigned int u32;
typedef unsigned short u16;

__device__ __forceinline__ u16 f2bf(float f) {
  u32 u = __float_as_uint(f);
  u += 0x7fffu + ((u >> 16) & 1u);   // RNE
  return (u16)(u >> 16);
}
__device__ __forceinline__ u32 pack2(float a, float b) {
  return (u32)f2bf(a) | ((u32)f2bf(b) << 16);
}
__device__ __forceinline__ void gload_lds16(const void* g, void* l) {
  __builtin_amdgcn_global_load_lds(
      (const __attribute__((address_space(1))) u32*)g,
      (__attribute__((address_space(3))) u32*)l, 16, 0, 0);
}

// ---------------- pre-pass: f32 -> bf16 (K, W) ----------------
__global__ void cvt_bf16_kernel(const float* __restrict__ in, u16* __restrict__ out,
                                long long n8) {
  long long i = (long long)blockIdx.x * blockDim.x + threadIdx.x;
  if (i >= n8) return;
  const float4* p = (const float4*)in + i * 2;
  float4 a = p[0], b = p[1];
  uint4 o;
  o.x = pack2(a.x, a.y); o.y = pack2(a.z, a.w);
  o.z = pack2(b.x, b.y); o.w = pack2(b.z, b.w);
  ((uint4*)out)[i] = o;
}

// ---------------- pre-pass: V[b][n][d] -> Vt[b][d][n] (bf16) ----------------
__global__ __launch_bounds__(256)
void transpose_v_kernel(const float* __restrict__ V, u16* __restrict__ Vt) {
  __shared__ float tile[64][65];
  const int n0 = blockIdx.x * 64, d0 = blockIdx.y * 64, bat = blockIdx.z;
  const int t = threadIdx.x;
  const int rr = t >> 4, cc = (t & 15) * 4;
#pragma unroll
  for (int i = 0; i < 4; ++i) {
    int r = i * 16 + rr;
    float4 v = *(const float4*)(V + ((size_t)(bat * 2048 + n0 + r)) * 512 + d0 + cc);
    tile[r][cc + 0] = v.x; tile[r][cc + 1] = v.y;
    tile[r][cc + 2] = v.z; tile[r][cc + 3] = v.w;
  }
  __syncthreads();
#pragma unroll
  for (int i = 0; i < 4; ++i) {
    int dr = i * 16 + rr;
    uint2 o;
    o.x = pack2(tile[cc + 0][dr], tile[cc + 1][dr]);
    o.y = pack2(tile[cc + 2][dr], tile[cc + 3][dr]);
    *(uint2*)(Vt + ((size_t)(bat * 512 + d0 + dr)) * 2048 + n0 + cc) = o;
  }
}

// ------- fused flash attention + projection (16 waves/CU, fixed reg cap):
//   R = relu(softmax(QK^T*s) @ V);  Out = a*R + b*relu((V-R) @ W^T)
// Grid 512 blocks (8 bat x 64 q-tiles of 32 rows) x 512 thr -> 4096 waves
// = 16 waves/CU (4/SIMD), 2 independent barrier domains per CU.
// __launch_bounds__(512,2): 2nd arg behaves as min BLOCKS/CU on this
// toolchain (r0:(512,2)->128 cap; r7:(512,4)->64 cap+spill) -> 128 VGPRs.
// Single K buffer: K(it+1) DMA issued after bar1 (K(it) dead), drained at
// bar2's implicit vmcnt(0). Q loads global->reg. PV loads V per-s (vr[4])
// to keep peak live regs <= 128.
// LDS (bytes), total 79264 -> 2 blocks/CU (158.5KB of 160KB):
//  Ks [64][1024B] bf16 XOR-swz @0     (65536)  (T=V-R tile in epilogue)
//  Ss [32][68] f32             @65536 (8704)
//  Ps [32][144B] bf16          @74240 (4608)
//  mrow/lrow/resc f32[32]      @78848/78976/79104
//  flg u32[8]                  @79232
#define ATT_LDS 79264

__global__ __launch_bounds__(512, 2)
void attn_kernel(const float* __restrict__ Qf, const u16* __restrict__ Kb,
                 const u16* __restrict__ Vtg, const float* __restrict__ Vg,
                 const u16* __restrict__ Wb, const float* __restrict__ sp,
                 const float* __restrict__ ap, const float* __restrict__ bp,
                 float* __restrict__ Out) {
  extern __shared__ char smem[];
  u16* Ks = (u16*)smem;
  float* Ss = (float*)(smem + 65536);
  u16* Ps = (u16*)(smem + 74240);
  float* mrow = (float*)(smem + 78848);
  float* lrow = (float*)(smem + 78976);
  float* resc = (float*)(smem + 79104);
  u32* flg = (u32*)(smem + 79232);

  const int tid = threadIdx.x, lane = tid & 63, wid = tid >> 6;
  const int bat = blockIdx.x, q0 = blockIdx.y * 32;  // blockIdx.x==bat -> XCD-batch locality
  const float scale = sp[0] * 0.04419417382415922f;  // 1/sqrt(512)
  const int l15 = lane & 15, l4 = lane >> 4;
  const int srow = tid >> 4, sseg = tid & 15;        // softmax: 16 thr/row, 32 rows
  const int rwD = wid >> 2, cwD = wid & 3;           // QK^T wave tile: 16q x 16kv

  // ---- prologue: Q direct global->reg, pre-scaled f32 -> bf16 fragments ----
  bf16x8 qf[16];
  {
    const float* qsrc = Qf + ((size_t)(bat * 2048 + q0 + rwD * 16 + l15)) * 512;
#pragma unroll
    for (int ks = 0; ks < 16; ++ks) {
      float4 x0 = *(const float4*)(qsrc + ks * 32 + l4 * 8);
      float4 x1 = *(const float4*)(qsrc + ks * 32 + l4 * 8 + 4);
      uint4 w;
      w.x = pack2(x0.x * scale, x0.y * scale); w.y = pack2(x0.z * scale, x0.w * scale);
      w.z = pack2(x1.x * scale, x1.y * scale); w.w = pack2(x1.z * scale, x1.w * scale);
      qf[ks] = *(bf16x8*)&w;
    }
  }

  // ---- stage K(0) via global_load_lds (source pre-swizzled per lane) ----
#pragma unroll
  for (int j = 0; j < 8; ++j) {
    int row = wid * 8 + j;
    gload_lds16(Kb + ((size_t)(bat * 2048 + row)) * 512 + ((lane ^ (row & 7)) * 8),
                (char*)Ks + row * 1024);
  }
  if (tid < 32) { mrow[tid] = -1e30f; lrow[tid] = 0.f; }

  f32x4 o[2][4];
#pragma unroll
  for (int a = 0; a < 2; ++a)
#pragma unroll
    for (int b = 0; b < 4; ++b) o[a][b] = (f32x4){0.f, 0.f, 0.f, 0.f};

  __syncthreads();  // K(0) resident + visible

  const int swB = (l15 & 7) << 4;

  for (int it = 0; it < 32; ++it) {
    // ---- QK^T: wave = 16 q-rows x 16 kv-cols, K=512, even/odd acc chains ----
    {
      f32x4 se = (f32x4){0.f, 0.f, 0.f, 0.f};
      f32x4 so = (f32x4){0.f, 0.f, 0.f, 0.f};
      const char* kb = (const char*)Ks + (cwD * 16 + l15) * 1024;
      __builtin_amdgcn_s_setprio(1);
#pragma unroll
      for (int ks = 0; ks < 16; ks += 2) {
        const int offe = (ks * 64 + l4 * 16) ^ swB;
        const int offo = ((ks + 1) * 64 + l4 * 16) ^ swB;
        bf16x8 be = *(const bf16x8*)(kb + offe);
        bf16x8 bo = *(const bf16x8*)(kb + offo);
        se = __builtin_amdgcn_mfma_f32_16x16x32_bf16(qf[ks], be, se, 0, 0, 0);
        so = __builtin_amdgcn_mfma_f32_16x16x32_bf16(qf[ks + 1], bo, so, 0, 0, 0);
      }
      __builtin_amdgcn_s_setprio(0);
      f32x4 s = se + so;
      const int r0 = rwD * 16 + l4 * 4;
      const int c0 = cwD * 16 + l15;
#pragma unroll
      for (int j = 0; j < 4; ++j) Ss[(r0 + j) * 68 + c0] = s[j];
    }
    __syncthreads();  // bar1: Ss visible; all K(it) reads complete

    // ---- stage K(it+1) into the SAME buffer (K(it) dead past bar1) ----
    if (it < 31) {
      const int kv1 = (it + 1) * 64;
#pragma unroll
      for (int j = 0; j < 8; ++j) {
        int row = wid * 8 + j;
        gload_lds16(Kb + ((size_t)(bat * 2048 + kv1 + row)) * 512 + ((lane ^ (row & 7)) * 8),
                    (char*)Ks + row * 1024);
      }
    }

    // ---- online softmax with defer-max (THR=8): 16 threads/row, 4 cols each ----
    {
      const int row = srow, g = sseg;
      float4 sv = *(const float4*)(Ss + row * 68 + g * 4);
      float mt = fmaxf(fmaxf(sv.x, sv.y), fmaxf(sv.z, sv.w));
#pragma unroll
      for (int off = 1; off < 16; off <<= 1) mt = fmaxf(mt, __shfl_xor(mt, off));
      const float mold = mrow[row];
      const bool exceed = (mt > mold + 8.0f);
      const float mnew = exceed ? mt : mold;  // deferred max; P bounded by e^8
      float p0 = __expf(sv.x - mnew), p1 = __expf(sv.y - mnew);
      float p2 = __expf(sv.z - mnew), p3 = __expf(sv.w - mnew);
      float ps = (p0 + p1) + (p2 + p3);
#pragma unroll
      for (int off = 1; off < 16; off <<= 1) ps += __shfl_xor(ps, off);
      if (g == 0) {
        float rs = exceed ? __expf(mold - mnew) : 1.0f;
        resc[row] = rs;
        lrow[row] = lrow[row] * rs + ps;
        mrow[row] = mnew;
      }
      int ex = __any(g == 0 && exceed);  // wave-uniform
      if (lane == 0) flg[wid] = ex ? 1u : 0u;
      uint2 pw;
      pw.x = pack2(p0, p1); pw.y = pack2(p2, p3);
      *(uint2*)((char*)Ps + row * 144 + g * 8) = pw;
    }
    __syncthreads();  // bar2: Ps/flags visible; K(it+1) DMA drained

    // ---- PV: conditional rescale, then wave = 32 q-rows x 64 d-cols, k=64 ----
    // V loaded per-s (vr[4]) to keep peak live registers <= 128.
    {
      const uint4* fp = (const uint4*)flg;
      uint4 fa = fp[0], fb = fp[1];
      u32 anyr = fa.x | fa.y | fa.z | fa.w | fb.x | fb.y | fb.z | fb.w;
      if (anyr) {
#pragma unroll
        for (int fr = 0; fr < 2; ++fr) {
          f32x4 rf = *(const f32x4*)(resc + fr * 16 + l4 * 4);
#pragma unroll
          for (int cf = 0; cf < 4; ++cf)
#pragma unroll
            for (int j = 0; j < 4; ++j) o[fr][cf][j] *= rf[j];
        }
      }
#pragma unroll
      for (int s = 0; s < 2; ++s) {
        uint4 vr[4];
#pragma unroll
        for (int cf = 0; cf < 4; ++cf)
          vr[cf] = *(const uint4*)(Vtg +
              ((size_t)(bat * 512 + wid * 64 + cf * 16 + l15)) * 2048 +
              it * 64 + s * 32 + l4 * 8);
        bf16x8 pa[2];
#pragma unroll
        for (int fr = 0; fr < 2; ++fr)
          pa[fr] = *(const bf16x8*)((const char*)Ps + (fr * 16 + l15) * 144 + s * 64 + l4 * 16);
        __builtin_amdgcn_s_setprio(1);
#pragma unroll
        for (int fr = 0; fr < 2; ++fr)
#pragma unroll
          for (int cf = 0; cf < 4; ++cf)
            o[fr][cf] = __builtin_amdgcn_mfma_f32_16x16x32_bf16(
                pa[fr], *(const bf16x8*)&vr[cf], o[fr][cf], 0, 0, 0);
        __builtin_amdgcn_s_setprio(0);
      }
    }
    // no trailing barrier: QK^T(it+1) reads Ks written pre-bar2; Ss(it+1) writes
    // ordered after all softmax(it) Ss reads by bar2.
  }

  // ======== fused epilogue ========
  // R = relu(O/l) in regs; T = V-R -> Ks span (bf16, swizzled);
  // C = T @ W^T; Out = a*R + b*relu(C)
  const float av = ap[0], bv = bp[0];
#pragma unroll
  for (int fr = 0; fr < 2; ++fr) {
    f32x4 lv = *(const f32x4*)(lrow + fr * 16 + l4 * 4);
    f32x4 inv;
#pragma unroll
    for (int j = 0; j < 4; ++j) inv[j] = 1.f / lv[j];
#pragma unroll
    for (int cf = 0; cf < 4; ++cf)
#pragma unroll
      for (int j = 0; j < 4; ++j)
        o[fr][cf][j] = fmaxf(o[fr][cf][j] * inv[j], 0.f);  // o now holds R
  }
  // write T = V - R (swizzled bf16) into Ks region (dead: PV reads only Ps/V)
  {
    u16* Ts = (u16*)smem;
#pragma unroll
    for (int fr = 0; fr < 2; ++fr)
#pragma unroll
      for (int cf = 0; cf < 4; ++cf) {
        const int col = wid * 64 + cf * 16 + l15;
#pragma unroll
        for (int j = 0; j < 4; ++j) {
          const int row = fr * 16 + l4 * 4 + j;
          float v = Vg[((size_t)(bat * 2048 + q0 + row)) * 512 + col];
          u16 t = f2bf(v - o[fr][cf][j]);
          *(u16*)((char*)Ts + row * 1024 + ((col * 2) ^ ((row & 7) << 4))) = t;
        }
      }
  }
  __syncthreads();  // T tile complete

  // projection GEMM: wave owns 32q x 64o (o-cols wid*64..+64), k=512
  f32x4 c2[2][4];
#pragma unroll
  for (int a = 0; a < 2; ++a)
#pragma unroll
    for (int b = 0; b < 4; ++b) c2[a][b] = (f32x4){0.f, 0.f, 0.f, 0.f};
  {
    const u16* Ts = (u16*)smem;
#pragma unroll
    for (int ks = 0; ks < 16; ++ks) {
      bf16x8 aT[2];
#pragma unroll
      for (int fr = 0; fr < 2; ++fr) {
        const int row = fr * 16 + l15;
        aT[fr] = *(const bf16x8*)((const char*)Ts + row * 1024 +
                                  ((ks * 64 + l4 * 16) ^ ((row & 7) << 4)));
      }
#pragma unroll
      for (int cf = 0; cf < 4; ++cf) {
        const int orow = wid * 64 + cf * 16 + l15;
        bf16x8 bw = *(const bf16x8*)(Wb + (size_t)orow * 512 + ks * 32 + l4 * 8);
#pragma unroll
        for (int fr = 0; fr < 2; ++fr)
          c2[fr][cf] = __builtin_amdgcn_mfma_f32_16x16x32_bf16(aT[fr], bw, c2[fr][cf], 0, 0, 0);
      }
    }
  }
  // combine + store
#pragma unroll
  for (int fr = 0; fr < 2; ++fr)
#pragma unroll
    for (int cf = 0; cf < 4; ++cf) {
      const int col = wid * 64 + cf * 16 + l15;
#pragma unroll
      for (int j = 0; j < 4; ++j) {
        const int row = fr * 16 + l4 * 4 + j;
        float c = fmaxf(c2[fr][cf][j], 0.f);
        Out[((size_t)(bat * 2048 + q0 + row)) * 512 + col] = av * o[fr][cf][j] + bv * c;
      }
    }
}

extern "C" void kernel_launch(void* const* d_in, const int* in_sizes, int n_in,
                              void* d_out, int out_size, void* d_ws, size_t ws_size,
                              hipStream_t stream) {
  const float* Q = (const float*)d_in[0];
  const float* K = (const float*)d_in[1];
  const float* V = (const float*)d_in[2];
  const float* W = (const float*)d_in[3];
  const float* sp = (const float*)d_in[4];
  const float* ap = (const float*)d_in[5];
  const float* bp = (const float*)d_in[6];
  float* out = (float*)d_out;

  const long long tEl = 8LL * 2048 * 512;  // 8388608 elems per tensor
  u16* Kb = (u16*)d_ws;
  u16* Vt = Kb + tEl;
  u16* Wb = Vt + tEl;

  cvt_bf16_kernel<<<4096, 256, 0, stream>>>(K, Kb, tEl / 8);
  cvt_bf16_kernel<<<128, 256, 0, stream>>>(W, Wb, (512LL * 512) / 8);
  transpose_v_kernel<<<dim3(32, 8, 8), 256, 0, stream>>>(V, Vt);

  hipFuncSetAttribute(reinterpret_cast<const void*>(attn_kernel),
                      hipFuncAttributeMaxDynamicSharedMemorySize, ATT_LDS);
  attn_kernel<<<dim3(8, 64), 512, ATT_LDS, stream>>>(Q, Kb, Vt, V, Wb, sp, ap, bp, out);
}